// Round 16
// baseline (91.789 us; speedup 1.0000x reference)
//
#include <hip/hip_runtime.h>

#define HH 256
#define WW 256
#define BB 4
#define HW (HH*WW)
#define N_ITER 20
#define EPSV 1e-8f

#define FUSE 4
#define TILE 32
#define HALO (2*FUSE)            // 8
#define EXT  (TILE + 2*HALO)     // 48
#define EPAD 49                  // odd row stride in float4 cells
#define NTHR 576                 // 24x24 threads, each owns a 2x2 px block

__device__ __forceinline__ float ldz(const float* __restrict__ p, int y, int x) {
    if ((unsigned)y < HH && (unsigned)x < WW) return p[y*WW + x];
    return 0.0f;
}

template<int FIRST, int LAST>
__global__ __launch_bounds__(NTHR)
void tvl1_fused(const float* __restrict__ xin,
                float* __restrict__ u,
                float4* __restrict__ p4,      // (p1c0,p1c1,p2c0,p2c1) per px
                float4* __restrict__ g4,      // (gx, gy, rc, 0) per px
                const float* __restrict__ lam, const float* __restrict__ tau,
                const float* __restrict__ the) {
    // All-b128 LDS (b64 empirically unsafe in LDS: R6/R10).
    // sp cell = (p1c0,p1c1,p2c0,p2c1); su cell = (u0,u1,0,0).
    // 2x2 ownership: each thread owns a 2x2 px block; one 4x4 window
    // (12 b128 reads, 4 own cells in regs) serves all 4 pixels per phase.
    __shared__ float4 su[EXT][EPAD];
    __shared__ float4 sp[EXT][EPAD];     // 2 * 48*49*16B = 75.3 KB

    const int tid = threadIdx.x;
    const int qx2 = (tid % 24) * 2;          // 0,2,...,46
    const int qy2 = (tid / 24) * 2;          // 0,2,...,46
    const int b  = blockIdx.z;
    const int ox = blockIdx.x*TILE - HALO;
    const int oy = blockIdx.y*TILE - HALO;
    const int pb = b*2*HW, cb = b*HW;
    const float theta = the[0];
    const float tl = theta * lam[0];
    const float r = tau[0] / theta;

    // clamped window row/col indices (clamps only feed dead, non-upd pixels)
    const int rI0 = (qy2 == 0)  ? 0  : qy2 - 1;
    const int rI3 = (qy2 == 46) ? 47 : qy2 + 2;
    const int cI0 = (qx2 == 0)  ? 0  : qx2 - 1;
    const int cI3 = (qx2 == 46) ? 47 : qx2 + 2;

    // per-own-pixel state: px index k = j*2+i, (ly,lx) = (qy2+j, qx2+i)
    float  ru0[4], ru1[4];
    float4 rp[4];                 // (p10,p11,p20,p21)
    float4 rg[4];                 // (gx,gy,rc,·)
    bool   updr[4];

    #pragma unroll
    for (int j = 0; j < 2; ++j)
      #pragma unroll
      for (int i = 0; i < 2; ++i) {
        int k = j*2 + i;
        int ly = qy2 + j, lx = qx2 + i;
        bool img = ((unsigned)(oy+ly) < HH) && ((unsigned)(ox+lx) < WW);
        // update set: in-image (SAME-pad zeros stay zero) + stencil-readable.
        // No ring shrinking: stale ring-h values are never read by a pixel
        // that remains valid (1 ring per half-step, halo = 8 = #half-steps).
        updr[k] = img && (ly >= 1) && (ly < EXT-1) && (lx >= 1) && (lx < EXT-1);
      }

    if (FIRST) {
        // ---- stage (im1, im0) into su; compute g in-LDS; u = p = 0 ----
        float im1r[4], im0r[4];
        #pragma unroll
        for (int j = 0; j < 2; ++j)
          #pragma unroll
          for (int i = 0; i < 2; ++i) {
            int k = j*2 + i;
            int ly = qy2 + j, lx = qx2 + i;
            im1r[k] = ldz(xin + pb + HW, oy+ly, ox+lx);
            im0r[k] = ldz(xin + pb,      oy+ly, ox+lx);
            su[ly][lx] = make_float4(im1r[k], im0r[k], 0.f, 0.f);
          }
        __syncthreads();
        {
            float4 W[4][4];
            W[0][0]=su[rI0][cI0]; W[0][1]=su[rI0][qx2]; W[0][2]=su[rI0][qx2+1]; W[0][3]=su[rI0][cI3];
            W[1][0]=su[qy2  ][cI0];                                             W[1][3]=su[qy2  ][cI3];
            W[2][0]=su[qy2+1][cI0];                                             W[2][3]=su[qy2+1][cI3];
            W[3][0]=su[rI3][cI0]; W[3][1]=su[rI3][qx2]; W[3][2]=su[rI3][qx2+1]; W[3][3]=su[rI3][cI3];
            W[1][1]=make_float4(im1r[0],im0r[0],0.f,0.f); W[1][2]=make_float4(im1r[1],im0r[1],0.f,0.f);
            W[2][1]=make_float4(im1r[2],im0r[2],0.f,0.f); W[2][2]=make_float4(im1r[3],im0r[3],0.f,0.f);
            #pragma unroll
            for (int j = 0; j < 2; ++j)
              #pragma unroll
              for (int i = 0; i < 2; ++i) {
                int k = j*2 + i;
                float gx_ = (W[j][i+2].x-W[j][i].x) + 2.f*(W[j+1][i+2].x-W[j+1][i].x) + (W[j+2][i+2].x-W[j+2][i].x);
                float gy_ = (W[j+2][i].x-W[j][i].x) + 2.f*(W[j+2][i+1].x-W[j][i+1].x) + (W[j+2][i+2].x-W[j][i+2].x);
                rg[k] = make_float4(gx_, gy_, im1r[k] - im0r[k], 0.f);
                ru0[k]=0.f; ru1[k]=0.f;
                rp[k] = make_float4(0.f,0.f,0.f,0.f);
                int ly = qy2 + j, lx = qx2 + i;
                if (ly >= HALO && ly < HALO+TILE && lx >= HALO && lx < HALO+TILE)
                    g4[cb + (oy+ly)*WW + (ox+lx)] = rg[k];
              }
        }
        __syncthreads();    // all windows read before su is repurposed
        #pragma unroll
        for (int j = 0; j < 2; ++j)
          #pragma unroll
          for (int i = 0; i < 2; ++i) {
            su[qy2+j][qx2+i] = make_float4(0.f,0.f,0.f,0.f);
            sp[qy2+j][qx2+i] = make_float4(0.f,0.f,0.f,0.f);
          }
        __syncthreads();
    } else {
        // ---- stage: 2 scalar + 2 b128 global loads per px ----
        #pragma unroll
        for (int j = 0; j < 2; ++j)
          #pragma unroll
          for (int i = 0; i < 2; ++i) {
            int k = j*2 + i;
            int ly = qy2 + j, lx = qx2 + i;
            bool img = ((unsigned)(oy+ly) < HH) && ((unsigned)(ox+lx) < WW);
            float v0=0.f, v1=0.f;
            float4 P = make_float4(0.f,0.f,0.f,0.f);
            float4 G = make_float4(0.f,0.f,0.f,0.f);
            if (img) {
                int gi = (oy+ly)*WW + (ox+lx);
                v0 = u[pb + gi];  v1 = u[pb + HW + gi];
                P  = p4[cb + gi];
                G  = g4[cb + gi];
            }
            ru0[k]=v0; ru1[k]=v1; rp[k]=P; rg[k]=G;
            su[ly][lx] = make_float4(v0, v1, 0.f, 0.f);
            sp[ly][lx] = P;
          }
        __syncthreads();
    }

    #pragma unroll
    for (int it = 0; it < FUSE; ++it) {
        // ---- u half-step: p window from LDS (12 b128), pointwise from regs ----
        {
            float4 W[4][4];
            W[0][0]=sp[rI0][cI0]; W[0][1]=sp[rI0][qx2]; W[0][2]=sp[rI0][qx2+1]; W[0][3]=sp[rI0][cI3];
            W[1][0]=sp[qy2  ][cI0];                                             W[1][3]=sp[qy2  ][cI3];
            W[2][0]=sp[qy2+1][cI0];                                             W[2][3]=sp[qy2+1][cI3];
            W[3][0]=sp[rI3][cI0]; W[3][1]=sp[rI3][qx2]; W[3][2]=sp[rI3][qx2+1]; W[3][3]=sp[rI3][cI3];
            W[1][1]=rp[0]; W[1][2]=rp[1]; W[2][1]=rp[2]; W[2][2]=rp[3];
            #pragma unroll
            for (int j = 0; j < 2; ++j)
              #pragma unroll
              for (int i = 0; i < 2; ++i) {
                int k = j*2 + i;
                if (updr[k]) {
                    // SBX over p1 (.x,.y); SBY over p2 (.z,.w)
                    float x0 = (W[j][i+2].x-W[j][i].x) + 2.f*(W[j+1][i+2].x-W[j+1][i].x) + (W[j+2][i+2].x-W[j+2][i].x);
                    float x1 = (W[j][i+2].y-W[j][i].y) + 2.f*(W[j+1][i+2].y-W[j+1][i].y) + (W[j+2][i+2].y-W[j+2][i].y);
                    float y0 = (W[j+2][i].z-W[j][i].z) + 2.f*(W[j+2][i+1].z-W[j][i+1].z) + (W[j+2][i+2].z-W[j][i+2].z);
                    float y1 = (W[j+2][i].w-W[j][i].w) + 2.f*(W[j+2][i+1].w-W[j][i+1].w) + (W[j+2][i+2].w-W[j][i+2].w);

                    float g_x = rg[k].x, g_y = rg[k].y;
                    float ng  = g_x*g_x + g_y*g_y + EPSV;
                    float rho = rg[k].z + g_x*ru0[k] + g_y*ru1[k];
                    float th  = tl * ng;
                    float sgn = (rho > 0.f) ? 1.f : ((rho < 0.f) ? -1.f : 0.f);
                    float dd  = (fabsf(rho) < th) ? (rho / ng) : (tl * sgn);
                    ru0[k] = ru0[k] - dd*g_x + theta*(x0 + y0);
                    ru1[k] = ru1[k] - dd*g_y + theta*(x1 + y1);
                    su[qy2+j][qx2+i] = make_float4(ru0[k], ru1[k], 0.f, 0.f);
                }
              }
        }
        __syncthreads();

        if (LAST && it == FUSE-1) break;    // 20th p-update never feeds the output

        // ---- p half-step: u window from LDS (12 b128), pointwise from regs ----
        {
            float4 V[4][4];
            V[0][0]=su[rI0][cI0]; V[0][1]=su[rI0][qx2]; V[0][2]=su[rI0][qx2+1]; V[0][3]=su[rI0][cI3];
            V[1][0]=su[qy2  ][cI0];                                             V[1][3]=su[qy2  ][cI3];
            V[2][0]=su[qy2+1][cI0];                                             V[2][3]=su[qy2+1][cI3];
            V[3][0]=su[rI3][cI0]; V[3][1]=su[rI3][qx2]; V[3][2]=su[rI3][qx2+1]; V[3][3]=su[rI3][cI3];
            V[1][1]=make_float4(ru0[0],ru1[0],0.f,0.f); V[1][2]=make_float4(ru0[1],ru1[1],0.f,0.f);
            V[2][1]=make_float4(ru0[2],ru1[2],0.f,0.f); V[2][2]=make_float4(ru0[3],ru1[3],0.f,0.f);
            #pragma unroll
            for (int j = 0; j < 2; ++j)
              #pragma unroll
              for (int i = 0; i < 2; ++i) {
                int k = j*2 + i;
                if (updr[k]) {
                    float g1x = (V[j][i+2].x-V[j][i].x) + 2.f*(V[j+1][i+2].x-V[j+1][i].x) + (V[j+2][i+2].x-V[j+2][i].x);
                    float g1y = (V[j+2][i].x-V[j][i].x) + 2.f*(V[j+2][i+1].x-V[j][i+1].x) + (V[j+2][i+2].x-V[j][i+2].x);
                    float g2x = (V[j][i+2].y-V[j][i].y) + 2.f*(V[j+1][i+2].y-V[j+1][i].y) + (V[j+2][i+2].y-V[j+2][i].y);
                    float g2y = (V[j+2][i].y-V[j][i].y) + 2.f*(V[j+2][i+1].y-V[j][i+1].y) + (V[j+2][i+2].y-V[j][i+2].y);
                    float inv1 = 1.f / (1.f + r*(fabsf(g1x) + fabsf(g1y)));
                    float inv2 = 1.f / (1.f + r*(fabsf(g2x) + fabsf(g2y)));
                    rp[k].x = (rp[k].x + r*g1x) * inv1;
                    rp[k].y = (rp[k].y + r*g1y) * inv1;
                    rp[k].z = (rp[k].z + r*g2x) * inv2;
                    rp[k].w = (rp[k].w + r*g2y) * inv2;
                    sp[qy2+j][qx2+i] = rp[k];
                }
              }
        }
        __syncthreads();
    }

    // ---- write back interior straight from registers ----
    #pragma unroll
    for (int j = 0; j < 2; ++j)
      #pragma unroll
      for (int i = 0; i < 2; ++i) {
        int k = j*2 + i;
        int ly = qy2 + j, lx = qx2 + i;
        if (updr[k] && ly >= HALO && ly < HALO+TILE && lx >= HALO && lx < HALO+TILE) {
            int go = (oy + ly)*WW + (ox + lx);
            u[pb + go]      = ru0[k];
            u[pb + HW + go] = ru1[k];
            if (!LAST)
                p4[cb + go] = rp[k];
        }
      }
}

extern "C" void kernel_launch(void* const* d_in, const int* in_sizes, int n_in,
                              void* d_out, int out_size, void* d_ws, size_t ws_size,
                              hipStream_t stream) {
    const float* xin = (const float*)d_in[0];
    const float* lam = (const float*)d_in[1];
    const float* tau = (const float*)d_in[2];
    const float* the = (const float*)d_in[3];
    float* u = (float*)d_out;              // u lives in d_out (B,2,H,W)

    // ws layout: packed float4 planes (16B-aligned by construction)
    float4* p4 = (float4*)d_ws;                    // BB*HW cells (4 MB)
    float4* g4 = p4 + (size_t)BB*HW;               // BB*HW cells (4 MB)

    dim3 blk(NTHR, 1, 1);
    dim3 grd(WW/TILE, HH/TILE, BB);        // 8 x 8 x 4 = 256 blocks = 1/CU
    tvl1_fused<1,0><<<grd, blk, 0, stream>>>(xin, u, p4, g4, lam, tau, the);
    tvl1_fused<0,0><<<grd, blk, 0, stream>>>(xin, u, p4, g4, lam, tau, the);
    tvl1_fused<0,0><<<grd, blk, 0, stream>>>(xin, u, p4, g4, lam, tau, the);
    tvl1_fused<0,0><<<grd, blk, 0, stream>>>(xin, u, p4, g4, lam, tau, the);
    tvl1_fused<0,1><<<grd, blk, 0, stream>>>(xin, u, p4, g4, lam, tau, the);
}

// Round 17
// 83.789 us; speedup vs baseline: 1.0955x; 1.0955x over previous
//
#include <hip/hip_runtime.h>

#define HH 256
#define WW 256
#define BB 4
#define HW (HH*WW)
#define N_ITER 20
#define EPSV 1e-8f

#define FUSE 4
#define TILE 32
#define HALO (2*FUSE)            // 8
#define EXT  (TILE + 2*HALO)     // 48
#define EPAD 49                  // odd row stride in float4 cells
#define NTHR 768                 // 16 strips of 3 rows x 48 cols
#define RPS  3                   // rows per strip

__device__ __forceinline__ float ldz(const float* __restrict__ p, int y, int x) {
    if ((unsigned)y < HH && (unsigned)x < WW) return p[y*WW + x];
    return 0.0f;
}

template<int FIRST, int LAST>
__global__ __launch_bounds__(NTHR)
void tvl1_fused(const float* __restrict__ xin,
                float* __restrict__ u,
                float4* __restrict__ p4,      // (p1c0,p1c1,p2c0,p2c1) per px
                float4* __restrict__ g4,      // (gx, gy, rc, 0) per px
                const float* __restrict__ lam, const float* __restrict__ tau,
                const float* __restrict__ the) {
    // All-b128 LDS (b64 empirically unsafe in LDS: R6/R10).
    // sp cell = (p1c0,p1c1,p2c0,p2c1); su cell = (u0,u1,0,0).
    // Each thread owns a 3-row column strip: own-column cells in regs;
    // one 5-row x 3-col window (12 b128 reads) serves all 3 pixels per phase.
    __shared__ float4 su[EXT][EPAD];
    __shared__ float4 sp[EXT][EPAD];     // 2 * 48*49*16B = 75.3 KB

    const int tid = threadIdx.x;
    const int sx  = tid % EXT;               // column 0..47 (const divisor)
    const int sy3 = (tid / EXT) * RPS;       // strip top row: 0,3,...,45
    const int b  = blockIdx.z;
    const int ox = blockIdx.x*TILE - HALO;
    const int oy = blockIdx.y*TILE - HALO;
    const int pb = b*2*HW, cb = b*HW;
    const float theta = the[0];
    const float tl = theta * lam[0];
    const float r = tau[0] / theta;

    const int gxx = ox + sx;
    const bool inx = ((unsigned)gxx < WW);

    float ru0[RPS], ru1[RPS], rp10[RPS], rp11[RPS], rp20[RPS], rp21[RPS];
    float rgx[RPS], rgy[RPS], rrc[RPS];
    bool updr[RPS];

    // Clamped window edges: taps of any upd pixel are in-bounds by
    // construction; clamped cells only feed dead (non-upd) computations.
    const int rT = (sy3 == 0) ? 0 : sy3 - 1;
    const int rB = (sy3 + RPS >= EXT) ? EXT-1 : sy3 + RPS;
    const int xm = (sx == 0) ? 0 : sx - 1;
    const int xp = (sx == EXT-1) ? EXT-1 : sx + 1;

    #pragma unroll
    for (int j = 0; j < RPS; ++j) {
        int ry = sy3 + j;
        bool img = inx && ((unsigned)(oy + ry) < HH);
        // update set: in-image (SAME-pad zeros stay zero) + stencil-readable.
        // No ring shrinking: stale ring-h values are never read by a pixel
        // that remains valid (1 ring per half-step, halo = 8 = #half-steps).
        updr[j] = img && (ry >= 1) && (ry < EXT-1) && (sx >= 1) && (sx < EXT-1);
    }

    if (FIRST) {
        // ---- stage (im1, im0) into su; compute g in-LDS; u = p = 0 ----
        float im1r[RPS], im0r[RPS];
        #pragma unroll
        for (int j = 0; j < RPS; ++j) {
            int gyy = oy + sy3 + j;
            im1r[j] = ldz(xin + pb + HW, gyy, gxx);
            im0r[j] = ldz(xin + pb,      gyy, gxx);
            su[sy3 + j][sx] = make_float4(im1r[j], im0r[j], 0.f, 0.f);
        }
        __syncthreads();
        {
            float4 Vm[RPS+2], Vc[RPS+2], Vp[RPS+2];   // V[i] = row sy3-1+i
            Vm[0] = su[rT][xm];     Vc[0] = su[rT][sx];   Vp[0] = su[rT][xp];
            Vm[1] = su[sy3  ][xm];                        Vp[1] = su[sy3  ][xp];
            Vm[2] = su[sy3+1][xm];                        Vp[2] = su[sy3+1][xp];
            Vm[3] = su[sy3+2][xm];                        Vp[3] = su[sy3+2][xp];
            Vm[4] = su[rB][xm];     Vc[4] = su[rB][sx];   Vp[4] = su[rB][xp];
            Vc[1] = make_float4(im1r[0], im0r[0], 0.f, 0.f);
            Vc[2] = make_float4(im1r[1], im0r[1], 0.f, 0.f);
            Vc[3] = make_float4(im1r[2], im0r[2], 0.f, 0.f);
            #pragma unroll
            for (int j = 0; j < RPS; ++j) {
                // sobel of im1 (.x): SX has no center column, SY no middle row
                rgx[j] = (Vp[j].x-Vm[j].x) + 2.f*(Vp[j+1].x-Vm[j+1].x) + (Vp[j+2].x-Vm[j+2].x);
                rgy[j] = (Vm[j+2].x-Vm[j].x) + 2.f*(Vc[j+2].x-Vc[j].x) + (Vp[j+2].x-Vp[j].x);
                rrc[j] = im1r[j] - im0r[j];
                ru0[j]=0.f; ru1[j]=0.f;
                rp10[j]=0.f; rp11[j]=0.f; rp20[j]=0.f; rp21[j]=0.f;
                // persist g for dispatches 2..5 (interior cells exactly
                // partition the image across blocks)
                int ry = sy3 + j;
                if (ry >= HALO && ry < HALO+TILE && sx >= HALO && sx < HALO+TILE) {
                    int gi = (oy + ry)*WW + gxx;
                    g4[cb + gi] = make_float4(rgx[j], rgy[j], rrc[j], 0.f);
                }
            }
        }
        __syncthreads();    // all windows read before su is repurposed
        #pragma unroll
        for (int j = 0; j < RPS; ++j) {
            su[sy3 + j][sx] = make_float4(0.f, 0.f, 0.f, 0.f);
            sp[sy3 + j][sx] = make_float4(0.f, 0.f, 0.f, 0.f);
        }
        __syncthreads();
    } else {
        // ---- stage: 2 scalar + 2 b128 global loads per cell ----
        #pragma unroll
        for (int j = 0; j < RPS; ++j) {
            int ry = sy3 + j;
            int gyy = oy + ry;
            bool img = inx && ((unsigned)gyy < HH);
            float v0=0.f, v1=0.f;
            float4 P = make_float4(0.f,0.f,0.f,0.f);
            float4 G = make_float4(0.f,0.f,0.f,0.f);
            if (img) {
                int gi = gyy*WW + gxx;
                v0 = u[pb + gi];   v1 = u[pb + HW + gi];
                P  = p4[cb + gi];
                G  = g4[cb + gi];
            }
            ru0[j]=v0; ru1[j]=v1;
            rp10[j]=P.x; rp11[j]=P.y; rp20[j]=P.z; rp21[j]=P.w;
            rgx[j]=G.x; rgy[j]=G.y; rrc[j]=G.z;
            su[ry][sx] = make_float4(v0, v1, 0.f, 0.f);
            sp[ry][sx] = P;
        }
        __syncthreads();
    }

    #pragma unroll
    for (int it = 0; it < FUSE; ++it) {
        // ---- u half-step: p window from LDS (12 b128), pointwise from regs ----
        {
            float4 Wm[RPS+2], Wc[RPS+2], Wp[RPS+2];    // W[i] = row sy3-1+i
            Wm[0] = sp[rT][xm];     Wc[0] = sp[rT][sx];   Wp[0] = sp[rT][xp];
            Wm[1] = sp[sy3  ][xm];                        Wp[1] = sp[sy3  ][xp];
            Wm[2] = sp[sy3+1][xm];                        Wp[2] = sp[sy3+1][xp];
            Wm[3] = sp[sy3+2][xm];                        Wp[3] = sp[sy3+2][xp];
            Wm[4] = sp[rB][xm];     Wc[4] = sp[rB][sx];   Wp[4] = sp[rB][xp];
            Wc[1] = make_float4(rp10[0], rp11[0], rp20[0], rp21[0]);
            Wc[2] = make_float4(rp10[1], rp11[1], rp20[1], rp21[1]);
            Wc[3] = make_float4(rp10[2], rp11[2], rp20[2], rp21[2]);
            #pragma unroll
            for (int j = 0; j < RPS; ++j) {
                if (updr[j]) {
                    // SBX over p1 (.x,.y): no center column
                    float x0 = (Wp[j].x-Wm[j].x) + 2.f*(Wp[j+1].x-Wm[j+1].x) + (Wp[j+2].x-Wm[j+2].x);
                    float x1 = (Wp[j].y-Wm[j].y) + 2.f*(Wp[j+1].y-Wm[j+1].y) + (Wp[j+2].y-Wm[j+2].y);
                    // SBY over p2 (.z,.w): no middle row
                    float y0 = (Wm[j+2].z-Wm[j].z) + 2.f*(Wc[j+2].z-Wc[j].z) + (Wp[j+2].z-Wp[j].z);
                    float y1 = (Wm[j+2].w-Wm[j].w) + 2.f*(Wc[j+2].w-Wc[j].w) + (Wp[j+2].w-Wp[j].w);

                    float g_x = rgx[j], g_y = rgy[j];
                    float ng  = g_x*g_x + g_y*g_y + EPSV;
                    float rho = rrc[j] + g_x*ru0[j] + g_y*ru1[j];
                    float th  = tl * ng;
                    float sgn = (rho > 0.f) ? 1.f : ((rho < 0.f) ? -1.f : 0.f);
                    float dd  = (fabsf(rho) < th) ? (rho / ng) : (tl * sgn);
                    ru0[j] = ru0[j] - dd*g_x + theta*(x0 + y0);
                    ru1[j] = ru1[j] - dd*g_y + theta*(x1 + y1);
                    su[sy3+j][sx] = make_float4(ru0[j], ru1[j], 0.f, 0.f);
                }
            }
        }
        __syncthreads();

        if (LAST && it == FUSE-1) break;    // 20th p-update never feeds the output

        // ---- p half-step: u window from LDS (12 b128), pointwise from regs ----
        {
            float4 Vm[RPS+2], Vc[RPS+2], Vp[RPS+2];
            Vm[0] = su[rT][xm];     Vc[0] = su[rT][sx];   Vp[0] = su[rT][xp];
            Vm[1] = su[sy3  ][xm];                        Vp[1] = su[sy3  ][xp];
            Vm[2] = su[sy3+1][xm];                        Vp[2] = su[sy3+1][xp];
            Vm[3] = su[sy3+2][xm];                        Vp[3] = su[sy3+2][xp];
            Vm[4] = su[rB][xm];     Vc[4] = su[rB][sx];   Vp[4] = su[rB][xp];
            Vc[1] = make_float4(ru0[0], ru1[0], 0.f, 0.f);
            Vc[2] = make_float4(ru0[1], ru1[1], 0.f, 0.f);
            Vc[3] = make_float4(ru0[2], ru1[2], 0.f, 0.f);
            #pragma unroll
            for (int j = 0; j < RPS; ++j) {
                if (updr[j]) {
                    float g1x = (Vp[j].x-Vm[j].x) + 2.f*(Vp[j+1].x-Vm[j+1].x) + (Vp[j+2].x-Vm[j+2].x);
                    float g1y = (Vm[j+2].x-Vm[j].x) + 2.f*(Vc[j+2].x-Vc[j].x) + (Vp[j+2].x-Vp[j].x);
                    float g2x = (Vp[j].y-Vm[j].y) + 2.f*(Vp[j+1].y-Vm[j+1].y) + (Vp[j+2].y-Vm[j+2].y);
                    float g2y = (Vm[j+2].y-Vm[j].y) + 2.f*(Vc[j+2].y-Vc[j].y) + (Vp[j+2].y-Vp[j].y);
                    float inv1 = 1.f / (1.f + r*(fabsf(g1x) + fabsf(g1y)));
                    float inv2 = 1.f / (1.f + r*(fabsf(g2x) + fabsf(g2y)));
                    rp10[j] = (rp10[j] + r*g1x) * inv1;
                    rp11[j] = (rp11[j] + r*g1y) * inv1;
                    rp20[j] = (rp20[j] + r*g2x) * inv2;
                    rp21[j] = (rp21[j] + r*g2y) * inv2;
                    sp[sy3+j][sx] = make_float4(rp10[j], rp11[j], rp20[j], rp21[j]);
                }
            }
        }
        __syncthreads();
    }

    // ---- write back interior straight from registers ----
    #pragma unroll
    for (int j = 0; j < RPS; ++j) {
        int ry = sy3 + j;
        if (updr[j] && ry >= HALO && ry < HALO+TILE && sx >= HALO && sx < HALO+TILE) {
            int go = (oy + ry)*WW + (ox + sx);
            u[pb + go]      = ru0[j];
            u[pb + HW + go] = ru1[j];
            if (!LAST)
                p4[cb + go] = make_float4(rp10[j], rp11[j], rp20[j], rp21[j]);
        }
    }
}

extern "C" void kernel_launch(void* const* d_in, const int* in_sizes, int n_in,
                              void* d_out, int out_size, void* d_ws, size_t ws_size,
                              hipStream_t stream) {
    const float* xin = (const float*)d_in[0];
    const float* lam = (const float*)d_in[1];
    const float* tau = (const float*)d_in[2];
    const float* the = (const float*)d_in[3];
    float* u = (float*)d_out;              // u lives in d_out (B,2,H,W)

    // ws layout: packed float4 planes (16B-aligned by construction)
    float4* p4 = (float4*)d_ws;                    // BB*HW cells (4 MB)
    float4* g4 = p4 + (size_t)BB*HW;               // BB*HW cells (4 MB)

    dim3 blk(NTHR, 1, 1);
    dim3 grd(WW/TILE, HH/TILE, BB);        // 8 x 8 x 4 = 256 blocks = 1/CU
    // 5 dispatches: init merged into kernel 1 (computes g in-LDS, starts
    // from u=p=0); packed p4/g4 cut staging to 4 loads / 3 stores per cell.
    tvl1_fused<1,0><<<grd, blk, 0, stream>>>(xin, u, p4, g4, lam, tau, the);
    tvl1_fused<0,0><<<grd, blk, 0, stream>>>(xin, u, p4, g4, lam, tau, the);
    tvl1_fused<0,0><<<grd, blk, 0, stream>>>(xin, u, p4, g4, lam, tau, the);
    tvl1_fused<0,0><<<grd, blk, 0, stream>>>(xin, u, p4, g4, lam, tau, the);
    tvl1_fused<0,1><<<grd, blk, 0, stream>>>(xin, u, p4, g4, lam, tau, the);
}